// Round 1
// 208.022 us; speedup vs baseline: 1.0517x; 1.0517x over previous
//
#include <hip/hip_runtime.h>

// Problem constants (fixed by setup_inputs)
#define B  32
#define H  56
#define W  56
#define C  256
#define CR 64
#define S  (H * W)              // 3136 spatial positions
#define CHUNKS 49               // spatial chunks per batch for GAP partials
#define ROWS_PER_CHUNK (S / CHUNKS)   // 64 rows -> 16 float4-iters/thread
#define C4 (C / 4)              // 64 float4 channel groups
#define BLOCKS_PER_B 784        // (S*C4)/256 float4-blocks per batch for scale

typedef float floatx4 __attribute__((ext_vector_type(4)));

// ---------------------------------------------------------------------------
// Kernel 1: partial global-average-pool sums.
// Grid: (CHUNKS, B) x 256. Thread t covers channel-group (t&63), spatial
// sub-offset (t>>6) -> fully coalesced 256-lane x 16B loads. 16 fixed iters.
// NOTE (R4 lesson): no device-scope fences/atomics here — per-block agent
// fences cost ~190 us of L2 writeback stalls on gfx950.
// ---------------------------------------------------------------------------
__global__ void gap_kernel(const float* __restrict__ x, float* __restrict__ part) {
    const int chunk = blockIdx.x;
    const int b     = blockIdx.y;
    const int t  = threadIdx.x;       // 0..255
    const int cg = t & 63;            // channel float4-group
    const int so = t >> 6;            // spatial sub-offset 0..3

    const float4* x4 = (const float4*)x
                     + (size_t)b * (S * C4)
                     + (size_t)(chunk * ROWS_PER_CHUNK) * C4
                     + (size_t)so * C4 + cg;

    float4 acc = make_float4(0.f, 0.f, 0.f, 0.f);
    #pragma unroll
    for (int i = 0; i < ROWS_PER_CHUNK / 4; ++i) {   // 16 iterations
        float4 v = x4[(size_t)i * 4 * C4];
        acc.x += v.x; acc.y += v.y; acc.z += v.z; acc.w += v.w;
    }

    __shared__ float4 sdata[256];
    sdata[t] = acc;
    __syncthreads();

    if (t < 64) {
        float4 a = sdata[t], b2 = sdata[t + 64], c2 = sdata[t + 128], d2 = sdata[t + 192];
        float4 tot;
        tot.x = a.x + b2.x + c2.x + d2.x;
        tot.y = a.y + b2.y + c2.y + d2.y;
        tot.z = a.z + b2.z + c2.z + d2.z;
        tot.w = a.w + b2.w + c2.w + d2.w;
        ((float4*)part)[(size_t)(b * CHUNKS + chunk) * 64 + t] = tot;
    }
}

// ---------------------------------------------------------------------------
// Kernel 2: reduce partials -> mean -> FC1 -> relu6 -> FC2 -> hsigmoid -> g
// Grid: B blocks x 256 threads. Tiny; LDS-resident.
// R0 change: FC1 now uses all 256 threads (quarter-split over C) instead of
// 64 — removes the 3/4-idle serial dot product.
// ---------------------------------------------------------------------------
__global__ void gate_kernel(const float* __restrict__ part,
                            const float* __restrict__ w1,
                            const float* __restrict__ w2,
                            float* __restrict__ g) {
    const int b = blockIdx.x;
    const int t = threadIdx.x;   // 0..255

    __shared__ float ss[C];
    __shared__ float s1p[4][CR];
    __shared__ float s1s[CR];

    float sum = 0.f;
    #pragma unroll 7
    for (int ch = 0; ch < CHUNKS; ++ch)
        sum += part[(size_t)(b * CHUNKS + ch) * C + t];   // coalesced over t
    ss[t] = sum * (1.0f / (float)S);
    __syncthreads();

    // FC1: s1[r] = sum_c ss[c]*w1[c,r]; 256 threads = 4 c-quarters x 64 r
    {
        const int r = t & 63;
        const int q = t >> 6;
        float a = 0.f;
        #pragma unroll 8
        for (int c = 0; c < C / 4; ++c)
            a += ss[q * 64 + c] * w1[(q * 64 + c) * CR + r];  // coalesced over r
        s1p[q][r] = a;
    }
    __syncthreads();

    if (t < CR) {
        float v = s1p[0][t] + s1p[1][t] + s1p[2][t] + s1p[3][t];
        s1s[t] = fminf(fmaxf(v, 0.f), 6.f);                   // ReLU6
    }
    __syncthreads();

    float s2 = 0.f;
    #pragma unroll 8
    for (int r = 0; r < CR; ++r)
        s2 += s1s[r] * w2[r * C + t];             // w2: [CR, C], coalesced over t
    g[b * C + t] = fminf(fmaxf(s2 + 3.f, 0.f), 6.f) * (1.f / 6.f);  // hsigmoid
}

// ---------------------------------------------------------------------------
// Kernel 3: out = x * g[b, c]. float4 loads (x L3-resident from kernel 1).
// R0 change: NORMAL stores instead of nontemporal. x (102.8MB) + out
// (102.8MB) = 205.6MB < 256MB Infinity Cache, so both fit: stores complete
// at L3 and HBM write-back drains lazily after the kernel, instead of the
// NT path stalling on raw HBM write BW.
// ---------------------------------------------------------------------------
__global__ void scale_kernel(const float* __restrict__ x,
                             const float* __restrict__ g,
                             float* __restrict__ out) {
    const int b = blockIdx.y;
    const size_t i4 = ((size_t)(b * BLOCKS_PER_B + blockIdx.x)) * 256 + threadIdx.x;

    floatx4 xv = ((const floatx4*)x)[i4];
    float4  gv = ((const float4*)g)[b * 64 + (threadIdx.x & 63)];
    floatx4 o;
    o.x = xv.x * gv.x;
    o.y = xv.y * gv.y;
    o.z = xv.z * gv.z;
    o.w = xv.w * gv.w;
    ((floatx4*)out)[i4] = o;
}

extern "C" void kernel_launch(void* const* d_in, const int* in_sizes, int n_in,
                              void* d_out, int out_size, void* d_ws, size_t ws_size,
                              hipStream_t stream) {
    const float* x  = (const float*)d_in[0];
    const float* w1 = (const float*)d_in[1];
    const float* w2 = (const float*)d_in[2];
    float* out = (float*)d_out;

    // workspace layout: part [B*CHUNKS*C] then g [B*C]
    float* part = (float*)d_ws;
    float* g    = part + (size_t)B * CHUNKS * C;

    gap_kernel  <<<dim3(CHUNKS, B),       256, 0, stream>>>(x, part);
    gate_kernel <<<B,                     256, 0, stream>>>(part, w1, w2, g);
    scale_kernel<<<dim3(BLOCKS_PER_B, B), 256, 0, stream>>>(x, g, out);
}